// Round 4
// baseline (842.767 us; speedup 1.0000x reference)
//
#include <hip/hip_runtime.h>
#include <math.h>

// ---------------------------------------------------------------------------
// SimpleGCN round 4:
//  - linearity swap: layer-2 aggregates hrelu at 128-dim, then GEMM2 with
//    fused bias/relu/segment-pool epilogue (few atomics).
//  - XCD-sliced aggregation: features stored slice-major [8][N][16cols] bf16;
//    block (bid&7) -> XCD slice; 3.2MB slice fits per-XCD L2. 8 edges/wave
//    in flight, shfl_xor cross-group reduce, nontemporal edge/out streams.
//  - fused launches: count||prep_w, dinv in scan1, fill||gemm1.
// ---------------------------------------------------------------------------

typedef __attribute__((ext_vector_type(4))) float f32x4;
typedef __attribute__((ext_vector_type(4))) float f4v;
typedef __attribute__((ext_vector_type(8))) short bf16x8;

static __device__ __forceinline__ ushort f2bf(float f) {
    union { float f; uint u; } v{f};
    uint r = (v.u + 0x7FFF + ((v.u >> 16) & 1)) >> 16;
    return (ushort)r;
}
static __device__ __forceinline__ float bflo(uint v) {
    union { uint u; float f; } o{v << 16};
    return o.f;
}
static __device__ __forceinline__ float bfhi(uint v) {
    union { uint u; float f; } o{v & 0xffff0000u};
    return o.f;
}

// ---- fused: degree count || weight prep ----------------------------------
__global__ __launch_bounds__(256) void k_count_prep(const int* __restrict__ dst,
                                                    int E, int* __restrict__ degi,
                                                    const float* __restrict__ W1,
                                                    const float* __restrict__ W2,
                                                    ushort* __restrict__ w1t,
                                                    ushort* __restrict__ w2t,
                                                    int cntBlocks) {
    int bid = blockIdx.x;
    if (bid < cntBlocks) {
        int e = bid * 256 + threadIdx.x;
        if (e < E) atomicAdd(&degi[__builtin_nontemporal_load(&dst[e])], 1);
    } else {
        int i = (bid - cntBlocks) * 256 + threadIdx.x;
        if (i < 128 * 128) {
            int n = i >> 7, k = i & 127;
            w1t[i] = f2bf(W1[k * 128 + n]);
        } else if (i < 128 * 128 + 48 * 128) {
            int j = i - 128 * 128;
            int n = j >> 7, k = j & 127;
            w2t[j] = (n < 40) ? f2bf(W2[k * 40 + n]) : (ushort)0;
        }
    }
}

// ---- scan level 1 (+ dinv fused) -----------------------------------------
__global__ __launch_bounds__(256) void k_scan1(const int* __restrict__ in,
                                               int* __restrict__ outp,  // rowptr+1
                                               int* __restrict__ bsums,
                                               float* __restrict__ dinv, int N) {
    __shared__ int sh[256];
    int t = threadIdx.x, b = blockIdx.x;
    int base = b * 1024 + t * 4;
    int v0 = (base + 0 < N) ? in[base + 0] : 0;
    int v1 = (base + 1 < N) ? in[base + 1] : 0;
    int v2 = (base + 2 < N) ? in[base + 2] : 0;
    int v3 = (base + 3 < N) ? in[base + 3] : 0;
    if (base + 0 < N) dinv[base + 0] = rsqrtf((float)v0 + 1.0f);
    if (base + 1 < N) dinv[base + 1] = rsqrtf((float)v1 + 1.0f);
    if (base + 2 < N) dinv[base + 2] = rsqrtf((float)v2 + 1.0f);
    if (base + 3 < N) dinv[base + 3] = rsqrtf((float)v3 + 1.0f);
    int l0 = v0, l1 = l0 + v1, l2 = l1 + v2, l3 = l2 + v3;
    sh[t] = l3;
    __syncthreads();
    int run = l3;
    for (int off = 1; off < 256; off <<= 1) {
        int y = (t >= off) ? sh[t - off] : 0;
        __syncthreads();
        run += y;
        sh[t] = run;
        __syncthreads();
    }
    int excl = run - l3;
    if (base + 0 < N) outp[base + 0] = excl + l0;
    if (base + 1 < N) outp[base + 1] = excl + l1;
    if (base + 2 < N) outp[base + 2] = excl + l2;
    if (base + 3 < N) outp[base + 3] = excl + l3;
    if (t == 255) bsums[b] = run;
}

__global__ __launch_bounds__(256) void k_scan2(const int* __restrict__ bsums,
                                               int* __restrict__ boffs, int nb) {
    __shared__ int sh[256];
    int t = threadIdx.x;
    int v = (t < nb) ? bsums[t] : 0;
    sh[t] = v;
    __syncthreads();
    int run = v;
    for (int off = 1; off < 256; off <<= 1) {
        int y = (t >= off) ? sh[t - off] : 0;
        __syncthreads();
        run += y;
        sh[t] = run;
        __syncthreads();
    }
    boffs[t] = run - v;  // exclusive
}

__global__ __launch_bounds__(256) void k_scan3(int* __restrict__ rowptr,
                                               const int* __restrict__ boffs,
                                               int* __restrict__ cursor, int N) {
    int i = blockIdx.x * 256 + threadIdx.x;
    if (i == 0) { rowptr[0] = 0; cursor[0] = 0; }
    if (i < N) {
        int v = rowptr[1 + i] + boffs[i >> 10];
        rowptr[1 + i] = v;
        if (i + 1 < N) cursor[i + 1] = v;
    }
}

// ---- fused: GEMM1 (x fp32 -> bf16 MFMA, slice-major C) || CSR fill --------
__global__ __launch_bounds__(256) void k_gemm1_fill(
    const float* __restrict__ A, const ushort* __restrict__ BT,
    ushort* __restrict__ C, int M, int gemmB,
    const int* __restrict__ src, const int* __restrict__ dst,
    const float* __restrict__ dinv, int E, int* __restrict__ cursor,
    long long* __restrict__ pairs) {
    __shared__ ushort As[64][136];
    __shared__ ushort Bs[128][136];
    const int tid = threadIdx.x;
    const int bid = blockIdx.x;
    const bool isg = (bid % 5 == 0) && (bid / 5 < gemmB);
    if (!isg) {
        // ---- fill body ----
        int gemmBefore = bid / 5 + 1;
        if (gemmBefore > gemmB) gemmBefore = gemmB;
        int e = (bid - gemmBefore) * 256 + tid;
        if (e < E) {
            int d = __builtin_nontemporal_load(&dst[e]);
            int s = __builtin_nontemporal_load(&src[e]);
            float c = dinv[s] * dinv[d];
            int p = atomicAdd(&cursor[d], 1);
            long long pv = ((long long)__float_as_int(c) << 32) | (uint)s;
            __builtin_nontemporal_store(pv, &pairs[p]);
        }
        return;
    }
    // ---- gemm1 body ----
    const int m0 = (bid / 5) * 64;
#pragma unroll
    for (int i = 0; i < 4; i++) {  // stage A fp32 -> bf16
        int chunk = tid + i * 256;
        int r = chunk >> 4, c8 = chunk & 15;
        f4v v0 = {0.f, 0.f, 0.f, 0.f}, v1 = {0.f, 0.f, 0.f, 0.f};
        if (m0 + r < M) {
            const f4v* p = (const f4v*)&A[(size_t)(m0 + r) * 128 + c8 * 8];
            v0 = __builtin_nontemporal_load(p);
            v1 = __builtin_nontemporal_load(p + 1);
        }
        ushort o[8];
        o[0] = f2bf(v0.x); o[1] = f2bf(v0.y); o[2] = f2bf(v0.z); o[3] = f2bf(v0.w);
        o[4] = f2bf(v1.x); o[5] = f2bf(v1.y); o[6] = f2bf(v1.z); o[7] = f2bf(v1.w);
        *(float4*)&As[r][c8 * 8] = *(float4*)o;
    }
#pragma unroll
    for (int i = 0; i < 8; i++) {  // stage B (w1t)
        int chunk = tid + i * 256;
        int r = chunk >> 4, c = chunk & 15;
        *(float4*)&Bs[r][c * 8] = *(const float4*)&BT[(size_t)r * 128 + c * 8];
    }
    __syncthreads();
    const int wave = tid >> 6, lane = tid & 63;
    const int arow = wave * 16 + (lane & 15);
    const int kgrp = (lane >> 4) * 8;
    f32x4 acc[8];
#pragma unroll
    for (int i = 0; i < 8; i++) acc[i] = (f32x4){0.f, 0.f, 0.f, 0.f};
#pragma unroll
    for (int kk = 0; kk < 4; kk++) {
        bf16x8 a = *(const bf16x8*)&As[arow][kk * 32 + kgrp];
#pragma unroll
        for (int nf = 0; nf < 8; nf++) {
            bf16x8 b = *(const bf16x8*)&Bs[nf * 16 + (lane & 15)][kk * 32 + kgrp];
            acc[nf] = __builtin_amdgcn_mfma_f32_16x16x32_bf16(a, b, acc[nf], 0, 0, 0);
        }
    }
    const int orow = m0 + wave * 16 + (lane >> 4) * 4;
#pragma unroll
    for (int nf = 0; nf < 8; nf++) {  // slice-major store: slice == nf
        size_t sbase = (size_t)nf * M * 16 + (lane & 15);
#pragma unroll
        for (int j = 0; j < 4; j++) {
            int r = orow + j;
            if (r < M)
                __builtin_nontemporal_store(f2bf(acc[nf][j]), &C[sbase + (size_t)r * 16]);
        }
    }
}

// ---- XCD-sliced 128-dim aggregation --------------------------------------
// features slice-major [8][N][16 cols] bf16. block slice = bid&7 (XCD),
// 4 waves/block = 4 nodes, per wave 8 edges in flight (8 lanes x uint each).
template <bool BIAS_RELU>
__global__ __launch_bounds__(256) void k_agg(const ushort* __restrict__ hin,
                                             const int* __restrict__ rowptr,
                                             const long long* __restrict__ pairs,
                                             const float* __restrict__ dinv,
                                             const float* __restrict__ bias,
                                             ushort* __restrict__ hout, int N) {
    const int slice = blockIdx.x & 7;
    const int node = (blockIdx.x >> 3) * 4 + (threadIdx.x >> 6);
    const int lane = threadIdx.x & 63;
    const int g = lane >> 3;  // edge sub-group 0..7
    const int l = lane & 7;   // uint index within 32B slice chunk
    if (node >= N) return;
    const uint* hu = (const uint*)hin;
    const size_t sl = (size_t)slice * N * 8;  // slice base (uints)
    const int beg = rowptr[node], end = rowptr[node + 1];
    float ax = 0.f, ay = 0.f;
#pragma unroll 2
    for (int e = beg; e < end; e += 8) {
        int ee = e + g;
        if (ee < end) {
            long long pv = __builtin_nontemporal_load(&pairs[ee]);
            int s = (int)(pv & 0xffffffffLL);
            float w = __int_as_float((int)(pv >> 32));
            uint v = hu[sl + (size_t)s * 8 + l];
            ax += w * bflo(v);
            ay += w * bfhi(v);
        }
    }
#pragma unroll
    for (int off = 8; off < 64; off <<= 1) {  // sum 8 edge-groups
        ax += __shfl_xor(ax, off);
        ay += __shfl_xor(ay, off);
    }
    if (lane < 8) {
        float dn = dinv[node];
        float ws = dn * dn;
        uint sv = hu[sl + (size_t)node * 8 + l];
        ax += ws * bflo(sv);
        ay += ws * bfhi(sv);
        if (BIAS_RELU) {
            float2 bb = *(const float2*)&bias[slice * 16 + l * 2];
            ax = fmaxf(ax + bb.x, 0.f);
            ay = fmaxf(ay + bb.y, 0.f);
        }
        uint packed = ((uint)f2bf(ay) << 16) | (uint)f2bf(ax);
        __builtin_nontemporal_store(packed, &((uint*)hout)[sl + (size_t)node * 8 + l]);
    }
}

// ---- GEMM2 (hagg slice-major @ W2) + bias/relu/segment-pool epilogue -----
__global__ __launch_bounds__(256) void k_gemm2_pool(const ushort* __restrict__ A,
                                                    const ushort* __restrict__ BT,
                                                    const float* __restrict__ b2,
                                                    const int* __restrict__ batch,
                                                    float* __restrict__ pooled,
                                                    int M) {
    __shared__ ushort As[64][136];
    __shared__ ushort Bs[48][136];
    __shared__ float smC[64][44];
    __shared__ int sbatch[64];
    const int tid = threadIdx.x;
    const int m0 = blockIdx.x * 64;
#pragma unroll
    for (int i = 0; i < 4; i++) {  // stage A from slice-major
        int chunk = tid + i * 256;
        int r = chunk >> 4, c8 = chunk & 15;
        float4 v = {0.f, 0.f, 0.f, 0.f};
        if (m0 + r < M)
            v = *(const float4*)&A[((size_t)(c8 >> 1) * M + (m0 + r)) * 16 + (c8 & 1) * 8];
        *(float4*)&As[r][c8 * 8] = v;
    }
#pragma unroll
    for (int i = 0; i < 3; i++) {  // stage B (w2t)
        int chunk = tid + i * 256;
        int r = chunk >> 4, c = chunk & 15;
        *(float4*)&Bs[r][c * 8] = *(const float4*)&BT[(size_t)r * 128 + c * 8];
    }
    if (tid < 64) sbatch[tid] = (m0 + tid < M) ? batch[m0 + tid] : -1;
    __syncthreads();
    const int wave = tid >> 6, lane = tid & 63;
    const int arow = wave * 16 + (lane & 15);
    const int kgrp = (lane >> 4) * 8;
    f32x4 acc[3];
#pragma unroll
    for (int i = 0; i < 3; i++) acc[i] = (f32x4){0.f, 0.f, 0.f, 0.f};
#pragma unroll
    for (int kk = 0; kk < 4; kk++) {
        bf16x8 a = *(const bf16x8*)&As[arow][kk * 32 + kgrp];
#pragma unroll
        for (int nf = 0; nf < 3; nf++) {
            bf16x8 b = *(const bf16x8*)&Bs[nf * 16 + (lane & 15)][kk * 32 + kgrp];
            acc[nf] = __builtin_amdgcn_mfma_f32_16x16x32_bf16(a, b, acc[nf], 0, 0, 0);
        }
    }
    const int orowl = wave * 16 + (lane >> 4) * 4;  // local row in tile
#pragma unroll
    for (int nf = 0; nf < 3; nf++) {
        int col = nf * 16 + (lane & 15);
        if (col < 40) {
#pragma unroll
            for (int j = 0; j < 4; j++) smC[orowl + j][col] = acc[nf][j];
        }
    }
    __syncthreads();
    // segment-pool 16 rows per quarter, run-length over sorted batch ids
    int q = tid >> 6, c = tid & 63;
    if (c < 40) {
        float bc = b2[c];
        float run = 0.f;
        int curg = -1;
        for (int r = q * 16; r < q * 16 + 16; ++r) {
            int gid = sbatch[r];
            if (gid < 0) break;
            float v = fmaxf(smC[r][c] + bc, 0.f);
            if (gid != curg) {
                if (curg >= 0) atomicAdd(&pooled[(size_t)curg * 40 + c], run);
                curg = gid;
                run = v;
            } else {
                run += v;
            }
        }
        if (curg >= 0) atomicAdd(&pooled[(size_t)curg * 40 + c], run);
    }
}

// ---- finish: mean + log_softmax ------------------------------------------
__global__ __launch_bounds__(64) void k_finish(const float* __restrict__ pooled,
                                               const int* __restrict__ batch, int N,
                                               int DOUT, float* __restrict__ out) {
    int g = blockIdx.x;
    int c = threadIdx.x;
    int lo = 0, hi = N;
    while (lo < hi) {
        int mid = (lo + hi) >> 1;
        if (batch[mid] < g) lo = mid + 1; else hi = mid;
    }
    int start = lo;
    hi = N;
    int lo2 = lo;
    while (lo2 < hi) {
        int mid = (lo2 + hi) >> 1;
        if (batch[mid] <= g) lo2 = mid + 1; else hi = mid;
    }
    int cnt = lo2 - start;
    float v = (c < DOUT) ? pooled[(size_t)g * DOUT + c] / fmaxf((float)cnt, 1.f) : -1e30f;
    float m = v;
#pragma unroll
    for (int o = 32; o; o >>= 1) m = fmaxf(m, __shfl_xor(m, o));
    float ex = (c < DOUT) ? expf(v - m) : 0.f;
    float s = ex;
#pragma unroll
    for (int o = 32; o; o >>= 1) s += __shfl_xor(s, o);
    if (c < DOUT) out[(size_t)g * DOUT + c] = (v - m) - logf(s);
}

extern "C" void kernel_launch(void* const* d_in, const int* in_sizes, int n_in,
                              void* d_out, int out_size, void* d_ws, size_t ws_size,
                              hipStream_t stream) {
    const float* x = (const float*)d_in[0];
    const int* src = (const int*)d_in[1];
    const int* dst = (const int*)d_in[2];
    const int* batch = (const int*)d_in[3];
    const float* W1 = (const float*)d_in[4];
    const float* b1 = (const float*)d_in[5];
    const float* W2 = (const float*)d_in[6];
    const float* b2 = (const float*)d_in[7];
    float* out = (float*)d_out;

    const int N = in_sizes[3];
    const int E = in_sizes[1];
    const int DOUT = in_sizes[7];
    const int G = out_size / DOUT;

    char* ws = (char*)d_ws;
    size_t off = 0;
    auto alloc = [&](size_t bytes) -> char* {
        char* p = ws + off;
        off += (bytes + 255) & ~(size_t)255;
        return p;
    };
    ushort* h1b = (ushort*)alloc((size_t)N * 128 * 2);   // slice-major; reused as hagg
    ushort* hrelu = (ushort*)alloc((size_t)N * 128 * 2); // slice-major
    long long* pairs = (long long*)alloc((size_t)E * 8);
    int* degi = (int*)alloc((size_t)N * 4);
    int* rowptr = (int*)alloc((size_t)(N + 1) * 4);
    int* cursor = (int*)alloc((size_t)N * 4);
    float* dinv = (float*)alloc((size_t)N * 4);
    int* bsums = (int*)alloc(256 * 4);
    int* boffs = (int*)alloc(256 * 4);
    ushort* w1t = (ushort*)alloc(128 * 128 * 2);
    ushort* w2t = (ushort*)alloc(48 * 128 * 2);
    float* pooled = (float*)alloc((size_t)G * DOUT * 4);

    ushort* hagg = h1b;  // h1b dead after agg1

    hipMemsetAsync(degi, 0, (size_t)N * 4, stream);
    hipMemsetAsync(pooled, 0, (size_t)G * DOUT * 4, stream);

    const int TB = 256;
    const int cntB = (E + TB - 1) / TB;
    const int prepB = (128 * 128 + 48 * 128 + TB - 1) / TB;
    k_count_prep<<<cntB + prepB, TB, 0, stream>>>(dst, E, degi, W1, W2, w1t, w2t, cntB);

    int nb = (N + 1023) / 1024;
    k_scan1<<<nb, TB, 0, stream>>>(degi, rowptr + 1, bsums, dinv, N);
    k_scan2<<<1, TB, 0, stream>>>(bsums, boffs, nb);
    k_scan3<<<(N + TB - 1) / TB, TB, 0, stream>>>(rowptr, boffs, cursor, N);

    // GEMM1 || CSR fill (interleaved 1:4 in one grid)
    const int gemmB = (N + 63) / 64;
    const int fillB = (E + TB - 1) / TB;
    k_gemm1_fill<<<gemmB + fillB, TB, 0, stream>>>(x, w1t, h1b, N, gemmB, src, dst,
                                                   dinv, E, cursor, pairs);

    // hrelu = relu(agg(h1b) + b1)   [XCD-sliced]
    k_agg<true><<<((N + 3) / 4) * 8, TB, 0, stream>>>(h1b, rowptr, pairs, dinv, b1,
                                                      hrelu, N);
    // hagg = agg(hrelu)             [XCD-sliced]
    k_agg<false><<<((N + 3) / 4) * 8, TB, 0, stream>>>(hrelu, rowptr, pairs, dinv,
                                                       nullptr, hagg, N);
    // pooled += relu(hagg @ W2 + b2) per graph (fused epilogue)
    k_gemm2_pool<<<(N + 63) / 64, TB, 0, stream>>>(hagg, w2t, b2, batch, pooled, N);
    // mean + log_softmax
    k_finish<<<G, 64, 0, stream>>>(pooled, batch, N, DOUT, out);
}

// Round 5
// 396.144 us; speedup vs baseline: 2.1274x; 2.1274x over previous
//
#include <hip/hip_runtime.h>
#include <math.h>

// ---------------------------------------------------------------------------
// SimpleGCN round 5: best-of structure (round 2/3) + LDS-staged edge pairs
// in the gather kernels for deep memory-level parallelism.
//   count||prep_w -> scan(+dinv) -> fill(packed int2) ; gemm1(fp32A->bf16 MFMA)
//   -> agg1(128d, LDS pairs, unroll8) -> gemm2 -> agg2(40d) -> pool+softmax
// ---------------------------------------------------------------------------

typedef __attribute__((ext_vector_type(4))) float f32x4;
typedef __attribute__((ext_vector_type(8))) short bf16x8;

static __device__ __forceinline__ ushort f2bf(float f) {
    union { float f; uint u; } v{f};
    uint r = (v.u + 0x7FFF + ((v.u >> 16) & 1)) >> 16;
    return (ushort)r;
}
static __device__ __forceinline__ float bflo(uint v) {
    union { uint u; float f; } o{v << 16};
    return o.f;
}
static __device__ __forceinline__ float bfhi(uint v) {
    union { uint u; float f; } o{v & 0xffff0000u};
    return o.f;
}
static __device__ __forceinline__ float bf2f(ushort h) {
    union { uint u; float f; } o{(uint)h << 16};
    return o.f;
}

// ---- fused: degree count || weight prep ----------------------------------
__global__ __launch_bounds__(256) void k_count_prep(const int* __restrict__ dst,
                                                    int E, int* __restrict__ degi,
                                                    const float* __restrict__ W1,
                                                    const float* __restrict__ W2,
                                                    ushort* __restrict__ w1t,
                                                    ushort* __restrict__ w2t,
                                                    int cntBlocks) {
    int bid = blockIdx.x;
    if (bid < cntBlocks) {
        int e = bid * 256 + threadIdx.x;
        if (e < E) atomicAdd(&degi[__builtin_nontemporal_load(&dst[e])], 1);
    } else {
        int i = (bid - cntBlocks) * 256 + threadIdx.x;
        if (i < 128 * 128) {
            int n = i >> 7, k = i & 127;
            w1t[i] = f2bf(W1[k * 128 + n]);
        } else if (i < 128 * 128 + 48 * 128) {
            int j = i - 128 * 128;
            int n = j >> 7, k = j & 127;
            w2t[j] = (n < 40) ? f2bf(W2[k * 40 + n]) : (ushort)0;
        }
    }
}

// ---- scan level 1 (+ dinv fused) -----------------------------------------
__global__ __launch_bounds__(256) void k_scan1(const int* __restrict__ in,
                                               int* __restrict__ outp,  // rowptr+1
                                               int* __restrict__ bsums,
                                               float* __restrict__ dinv, int N) {
    __shared__ int sh[256];
    int t = threadIdx.x, b = blockIdx.x;
    int base = b * 1024 + t * 4;
    int v0 = (base + 0 < N) ? in[base + 0] : 0;
    int v1 = (base + 1 < N) ? in[base + 1] : 0;
    int v2 = (base + 2 < N) ? in[base + 2] : 0;
    int v3 = (base + 3 < N) ? in[base + 3] : 0;
    if (base + 0 < N) dinv[base + 0] = rsqrtf((float)v0 + 1.0f);
    if (base + 1 < N) dinv[base + 1] = rsqrtf((float)v1 + 1.0f);
    if (base + 2 < N) dinv[base + 2] = rsqrtf((float)v2 + 1.0f);
    if (base + 3 < N) dinv[base + 3] = rsqrtf((float)v3 + 1.0f);
    int l0 = v0, l1 = l0 + v1, l2 = l1 + v2, l3 = l2 + v3;
    sh[t] = l3;
    __syncthreads();
    int run = l3;
    for (int off = 1; off < 256; off <<= 1) {
        int y = (t >= off) ? sh[t - off] : 0;
        __syncthreads();
        run += y;
        sh[t] = run;
        __syncthreads();
    }
    int excl = run - l3;
    if (base + 0 < N) outp[base + 0] = excl + l0;
    if (base + 1 < N) outp[base + 1] = excl + l1;
    if (base + 2 < N) outp[base + 2] = excl + l2;
    if (base + 3 < N) outp[base + 3] = excl + l3;
    if (t == 255) bsums[b] = run;
}

__global__ __launch_bounds__(256) void k_scan2(const int* __restrict__ bsums,
                                               int* __restrict__ boffs, int nb) {
    __shared__ int sh[256];
    int t = threadIdx.x;
    int v = (t < nb) ? bsums[t] : 0;
    sh[t] = v;
    __syncthreads();
    int run = v;
    for (int off = 1; off < 256; off <<= 1) {
        int y = (t >= off) ? sh[t - off] : 0;
        __syncthreads();
        run += y;
        sh[t] = run;
        __syncthreads();
    }
    boffs[t] = run - v;  // exclusive
}

__global__ __launch_bounds__(256) void k_scan3(int* __restrict__ rowptr,
                                               const int* __restrict__ boffs,
                                               int* __restrict__ cursor, int N) {
    int i = blockIdx.x * 256 + threadIdx.x;
    if (i == 0) { rowptr[0] = 0; cursor[0] = 0; }
    if (i < N) {
        int v = rowptr[1 + i] + boffs[i >> 10];
        rowptr[1 + i] = v;
        if (i + 1 < N) cursor[i + 1] = v;
    }
}

// ---- CSR fill: single 8B packed scatter per edge -------------------------
__global__ __launch_bounds__(256) void k_fill(const int* __restrict__ src,
                                              const int* __restrict__ dst,
                                              const float* __restrict__ dinv, int E,
                                              int* __restrict__ cursor,
                                              int2* __restrict__ pairs) {
    int e = blockIdx.x * 256 + threadIdx.x;
    if (e < E) {
        int d = __builtin_nontemporal_load(&dst[e]);
        int s = __builtin_nontemporal_load(&src[e]);
        float c = dinv[s] * dinv[d];
        int p = atomicAdd(&cursor[d], 1);
        int2 pr;
        pr.x = s;
        pr.y = __float_as_int(c);
        pairs[p] = pr;
    }
}

// ---- GEMM1: A fp32 [M,128] (cast in staging) @ BT bf16 -> C bf16 ---------
template <int NF>
__global__ __launch_bounds__(256) void k_gemm_f32a(const float* __restrict__ A,
                                                   const ushort* __restrict__ BT,
                                                   ushort* __restrict__ C, int M,
                                                   int NCOLS) {
    __shared__ ushort As[64][136];
    __shared__ ushort Bs[NF * 16][136];
    const int tid = threadIdx.x;
    const int m0 = blockIdx.x * 64;
#pragma unroll
    for (int i = 0; i < 4; i++) {  // 1024 chunks of 8 elems (fp32 -> bf16)
        int chunk = tid + i * 256;
        int r = chunk >> 4, c8 = chunk & 15;
        float4 v0 = {0.f, 0.f, 0.f, 0.f}, v1 = {0.f, 0.f, 0.f, 0.f};
        if (m0 + r < M) {
            const float* p = &A[(size_t)(m0 + r) * 128 + c8 * 8];
            v0 = *(const float4*)p;
            v1 = *(const float4*)(p + 4);
        }
        ushort o[8];
        o[0] = f2bf(v0.x); o[1] = f2bf(v0.y); o[2] = f2bf(v0.z); o[3] = f2bf(v0.w);
        o[4] = f2bf(v1.x); o[5] = f2bf(v1.y); o[6] = f2bf(v1.z); o[7] = f2bf(v1.w);
        *(float4*)&As[r][c8 * 8] = *(float4*)o;
    }
#pragma unroll
    for (int i = 0; i < NF; i++) {  // stage B: NF*16 rows x 16 chunks
        int chunk = tid + i * 256;
        int r = chunk >> 4, c = chunk & 15;
        *(float4*)&Bs[r][c * 8] = *(const float4*)&BT[(size_t)r * 128 + c * 8];
    }
    __syncthreads();
    const int wave = tid >> 6, lane = tid & 63;
    const int arow = wave * 16 + (lane & 15);
    const int kgrp = (lane >> 4) * 8;
    f32x4 acc[NF];
#pragma unroll
    for (int i = 0; i < NF; i++) acc[i] = (f32x4){0.f, 0.f, 0.f, 0.f};
#pragma unroll
    for (int kk = 0; kk < 4; kk++) {
        bf16x8 a = *(const bf16x8*)&As[arow][kk * 32 + kgrp];
#pragma unroll
        for (int nf = 0; nf < NF; nf++) {
            bf16x8 b = *(const bf16x8*)&Bs[nf * 16 + (lane & 15)][kk * 32 + kgrp];
            acc[nf] = __builtin_amdgcn_mfma_f32_16x16x32_bf16(a, b, acc[nf], 0, 0, 0);
        }
    }
    const int orow = m0 + wave * 16 + (lane >> 4) * 4;
#pragma unroll
    for (int nf = 0; nf < NF; nf++) {
        int col = nf * 16 + (lane & 15);
        if (col >= NCOLS) continue;
#pragma unroll
        for (int j = 0; j < 4; j++) {
            int r = orow + j;
            if (r < M) C[(size_t)r * NCOLS + col] = f2bf(acc[nf][j]);
        }
    }
}

// ---- GEMM2: A bf16 @ BT bf16 -> C bf16 -----------------------------------
template <int NF>
__global__ __launch_bounds__(256) void k_gemm_bf16(const ushort* __restrict__ A,
                                                   const ushort* __restrict__ BT,
                                                   ushort* __restrict__ C, int M,
                                                   int NCOLS) {
    __shared__ ushort As[64][136];
    __shared__ ushort Bs[NF * 16][136];
    const int tid = threadIdx.x;
    const int m0 = blockIdx.x * 64;
#pragma unroll
    for (int i = 0; i < 4; i++) {
        int chunk = tid + i * 256;
        int r = chunk >> 4, c = chunk & 15;
        float4 v = {0.f, 0.f, 0.f, 0.f};
        if (m0 + r < M) v = *(const float4*)&A[((size_t)(m0 + r)) * 128 + c * 8];
        *(float4*)&As[r][c * 8] = v;
    }
#pragma unroll
    for (int i = 0; i < NF; i++) {
        int chunk = tid + i * 256;
        int r = chunk >> 4, c = chunk & 15;
        *(float4*)&Bs[r][c * 8] = *(const float4*)&BT[(size_t)r * 128 + c * 8];
    }
    __syncthreads();
    const int wave = tid >> 6, lane = tid & 63;
    const int arow = wave * 16 + (lane & 15);
    const int kgrp = (lane >> 4) * 8;
    f32x4 acc[NF];
#pragma unroll
    for (int i = 0; i < NF; i++) acc[i] = (f32x4){0.f, 0.f, 0.f, 0.f};
#pragma unroll
    for (int kk = 0; kk < 4; kk++) {
        bf16x8 a = *(const bf16x8*)&As[arow][kk * 32 + kgrp];
#pragma unroll
        for (int nf = 0; nf < NF; nf++) {
            bf16x8 b = *(const bf16x8*)&Bs[nf * 16 + (lane & 15)][kk * 32 + kgrp];
            acc[nf] = __builtin_amdgcn_mfma_f32_16x16x32_bf16(a, b, acc[nf], 0, 0, 0);
        }
    }
    const int orow = m0 + wave * 16 + (lane >> 4) * 4;
#pragma unroll
    for (int nf = 0; nf < NF; nf++) {
        int col = nf * 16 + (lane & 15);
        if (col >= NCOLS) continue;
#pragma unroll
        for (int j = 0; j < 4; j++) {
            int r = orow + j;
            if (r < M) C[(size_t)r * NCOLS + col] = f2bf(acc[nf][j]);
        }
    }
}

// ---- layer-1 aggregation: LDS-staged pairs, 8 gathers in flight ----------
__global__ __launch_bounds__(256) void k_agg1(const ushort* __restrict__ h1b,
                                              const int* __restrict__ rowptr,
                                              const int2* __restrict__ pairs,
                                              const float* __restrict__ dinv,
                                              const float* __restrict__ b1,
                                              ushort* __restrict__ outb, int N) {
    __shared__ int2 sp[4][64];
    const int w = threadIdx.x >> 6;
    const int lane = threadIdx.x & 63;
    const int wid = (blockIdx.x * 256 + threadIdx.x) >> 6;
    if (wid >= N) return;
    const uint* hu = (const uint*)h1b;  // 2 bf16 per lane
    const int beg = rowptr[wid], end = rowptr[wid + 1];
    float ax = 0.f, ay = 0.f;
    for (int base = beg; base < end; base += 64) {
        int cnt = min(64, end - base);
        if (lane < cnt) sp[w][lane] = pairs[base + lane];  // wave-private chunk
        int i = 0;
        for (; i + 8 <= cnt; i += 8) {
            uint v[8];
            float cw[8];
#pragma unroll
            for (int j = 0; j < 8; j++) {
                int2 p = sp[w][i + j];
                cw[j] = __int_as_float(p.y);
                v[j] = hu[(size_t)p.x * 64 + lane];
            }
#pragma unroll
            for (int j = 0; j < 8; j++) {
                ax += cw[j] * bflo(v[j]);
                ay += cw[j] * bfhi(v[j]);
            }
        }
        for (; i < cnt; ++i) {
            int2 p = sp[w][i];
            float cw = __int_as_float(p.y);
            uint vv = hu[(size_t)p.x * 64 + lane];
            ax += cw * bflo(vv);
            ay += cw * bfhi(vv);
        }
    }
    float dn = dinv[wid];
    uint sv = hu[(size_t)wid * 64 + lane];
    float ws = dn * dn;
    ax += ws * bflo(sv);
    ay += ws * bfhi(sv);
    float2 bb = *(const float2*)&b1[lane * 2];
    ax = fmaxf(ax + bb.x, 0.f);
    ay = fmaxf(ay + bb.y, 0.f);
    uint packed = ((uint)f2bf(ay) << 16) | (uint)f2bf(ax);
    __builtin_nontemporal_store(packed, &((uint*)outb)[(size_t)wid * 64 + lane]);
}

// ---- layer-2 aggregation: DOUT=40, LDS-staged pairs, unroll 8 ------------
__global__ __launch_bounds__(256) void k_agg2(const ushort* __restrict__ h2b,
                                              const int* __restrict__ rowptr,
                                              const int2* __restrict__ pairs,
                                              const float* __restrict__ dinv,
                                              const float* __restrict__ b2,
                                              float* __restrict__ h2a, int N,
                                              int DOUT) {
    __shared__ int2 sp[4][64];
    const int w = threadIdx.x >> 6;
    const int lane = threadIdx.x & 63;
    const int wid = (blockIdx.x * 256 + threadIdx.x) >> 6;
    if (wid >= N) return;
    const int beg = rowptr[wid], end = rowptr[wid + 1];
    float acc = 0.f;
    bool act = lane < DOUT;
    for (int base = beg; base < end; base += 64) {
        int cnt = min(64, end - base);
        if (lane < cnt) sp[w][lane] = pairs[base + lane];
        int i = 0;
        for (; i + 8 <= cnt; i += 8) {
            float v[8];
            float cw[8];
#pragma unroll
            for (int j = 0; j < 8; j++) {
                int2 p = sp[w][i + j];
                cw[j] = __int_as_float(p.y);
                v[j] = act ? bf2f(h2b[(size_t)p.x * DOUT + lane]) : 0.f;
            }
#pragma unroll
            for (int j = 0; j < 8; j++) acc += cw[j] * v[j];
        }
        for (; i < cnt; ++i) {
            int2 p = sp[w][i];
            if (act) acc += __int_as_float(p.y) * bf2f(h2b[(size_t)p.x * DOUT + lane]);
        }
    }
    if (!act) return;
    float dn = dinv[wid];
    acc += dn * dn * bf2f(h2b[(size_t)wid * DOUT + lane]);
    acc = fmaxf(acc + b2[lane], 0.f);
    __builtin_nontemporal_store(acc, &h2a[(size_t)wid * DOUT + lane]);
}

// ---- segment mean pool (batch sorted) + log_softmax ----------------------
__global__ __launch_bounds__(256) void k_pool(const float* __restrict__ h2a,
                                              const int* __restrict__ batch, int N,
                                              int DOUT, float* __restrict__ out) {
    int g = blockIdx.x;
    int t = threadIdx.x;
    int lo = 0, hi = N;
    while (lo < hi) {
        int mid = (lo + hi) >> 1;
        if (batch[mid] < g) lo = mid + 1; else hi = mid;
    }
    int start = lo;
    hi = N;
    while (lo < hi) {
        int mid = (lo + hi) >> 1;
        if (batch[mid] <= g) lo = mid + 1; else hi = mid;
    }
    int end = lo;
    int cnt = end - start;
    int c = t & 63, rr = t >> 6;
    float acc = 0.f;
    if (c < DOUT) {
        for (int i = start + rr; i < end; i += 4) acc += h2a[(size_t)i * DOUT + c];
    }
    __shared__ float sm[4][64];
    sm[rr][c] = acc;
    __syncthreads();
    if (t < 64) {
        float v = (c < DOUT)
                      ? (sm[0][c] + sm[1][c] + sm[2][c] + sm[3][c]) / fmaxf((float)cnt, 1.f)
                      : -1e30f;
        float m = v;
#pragma unroll
        for (int o = 32; o; o >>= 1) m = fmaxf(m, __shfl_xor(m, o));
        float ex = (c < DOUT) ? expf(v - m) : 0.f;
        float s = ex;
#pragma unroll
        for (int o = 32; o; o >>= 1) s += __shfl_xor(s, o);
        if (c < DOUT) out[g * DOUT + c] = (v - m) - logf(s);
    }
}

extern "C" void kernel_launch(void* const* d_in, const int* in_sizes, int n_in,
                              void* d_out, int out_size, void* d_ws, size_t ws_size,
                              hipStream_t stream) {
    const float* x = (const float*)d_in[0];
    const int* src = (const int*)d_in[1];
    const int* dst = (const int*)d_in[2];
    const int* batch = (const int*)d_in[3];
    const float* W1 = (const float*)d_in[4];
    const float* b1 = (const float*)d_in[5];
    const float* W2 = (const float*)d_in[6];
    const float* b2 = (const float*)d_in[7];
    float* out = (float*)d_out;

    const int N = in_sizes[3];
    const int E = in_sizes[1];
    const int DOUT = in_sizes[7];
    const int G = out_size / DOUT;

    char* ws = (char*)d_ws;
    size_t off = 0;
    auto alloc = [&](size_t bytes) -> char* {
        char* p = ws + off;
        off += (bytes + 255) & ~(size_t)255;
        return p;
    };
    ushort* h1b = (ushort*)alloc((size_t)N * 128 * 2);   // reused as h2b / h2a
    ushort* hrelu = (ushort*)alloc((size_t)N * 128 * 2);
    int2* pairs = (int2*)alloc((size_t)E * 8);
    int* degi = (int*)alloc((size_t)N * 4);
    int* rowptr = (int*)alloc((size_t)(N + 1) * 4);
    int* cursor = (int*)alloc((size_t)N * 4);
    float* dinv = (float*)alloc((size_t)N * 4);
    int* bsums = (int*)alloc(256 * 4);
    int* boffs = (int*)alloc(256 * 4);
    ushort* w1t = (ushort*)alloc(128 * 128 * 2);
    ushort* w2t = (ushort*)alloc(48 * 128 * 2);

    ushort* h2b = h1b;                           // [N][40] bf16, h1b dead after agg1
    float* h2a = (float*)(h1b + (size_t)N * 48); // [N][40] fp32, disjoint from h2b

    hipMemsetAsync(degi, 0, (size_t)N * 4, stream);

    const int TB = 256;
    const int cntB = (E + TB - 1) / TB;
    const int prepB = (128 * 128 + 48 * 128 + TB - 1) / TB;
    k_count_prep<<<cntB + prepB, TB, 0, stream>>>(dst, E, degi, W1, W2, w1t, w2t, cntB);

    int nb = (N + 1023) / 1024;
    k_scan1<<<nb, TB, 0, stream>>>(degi, rowptr + 1, bsums, dinv, N);
    k_scan2<<<1, TB, 0, stream>>>(bsums, boffs, nb);
    k_scan3<<<(N + TB - 1) / TB, TB, 0, stream>>>(rowptr, boffs, cursor, N);
    k_fill<<<(E + TB - 1) / TB, TB, 0, stream>>>(src, dst, dinv, E, cursor, pairs);

    // h1b = bf16(x) @ W1
    k_gemm_f32a<8><<<(N + 63) / 64, TB, 0, stream>>>(x, w1t, h1b, N, 128);
    // hrelu = relu(agg(h1b) + b1)
    k_agg1<<<(N + 3) / 4, TB, 0, stream>>>(h1b, rowptr, pairs, dinv, b1, hrelu, N);
    // h2b = hrelu @ W2
    k_gemm_bf16<3><<<(N + 63) / 64, TB, 0, stream>>>(hrelu, w2t, h2b, N, DOUT);
    // h2a = relu(agg(h2b) + b2)
    k_agg2<<<(N + 3) / 4, TB, 0, stream>>>(h2b, rowptr, pairs, dinv, b2, h2a, N, DOUT);
    // pooled mean + log_softmax
    k_pool<<<G, TB, 0, stream>>>(h2a, batch, N, DOUT, out);
}

// Round 7
// 342.272 us; speedup vs baseline: 2.4623x; 1.1574x over previous
//
#include <hip/hip_runtime.h>
#include <math.h>

// ---------------------------------------------------------------------------
// SimpleGCN round 7 (= round 6 + compile fix: ext_vector uint2 for
// nontemporal store):
//  - linearity swap: layer2 = agg128(hrelu) then GEMM2 with fused
//    bias/relu/segment-pool epilogue (no 40-dim gather, no separate pool).
//  - agg128: 2 edges per wave-instruction (8B/lane, half-waves), LDS-staged
//    pairs, unroll 8 edges -> 4 independent 8B gathers in flight per half.
//  - keeps: packed int2 fill, count||prep_w, dinv||scan1, fp32->bf16 GEMM1.
// ---------------------------------------------------------------------------

typedef __attribute__((ext_vector_type(4))) float f32x4;
typedef __attribute__((ext_vector_type(8))) short bf16x8;
typedef __attribute__((ext_vector_type(2))) uint uint2v;

static __device__ __forceinline__ ushort f2bf(float f) {
    union { float f; uint u; } v{f};
    uint r = (v.u + 0x7FFF + ((v.u >> 16) & 1)) >> 16;
    return (ushort)r;
}
static __device__ __forceinline__ float bflo(uint v) {
    union { uint u; float f; } o{v << 16};
    return o.f;
}
static __device__ __forceinline__ float bfhi(uint v) {
    union { uint u; float f; } o{v & 0xffff0000u};
    return o.f;
}

// ---- fused: degree count || weight prep ----------------------------------
__global__ __launch_bounds__(256) void k_count_prep(const int* __restrict__ dst,
                                                    int E, int* __restrict__ degi,
                                                    const float* __restrict__ W1,
                                                    const float* __restrict__ W2,
                                                    ushort* __restrict__ w1t,
                                                    ushort* __restrict__ w2t,
                                                    int cntBlocks) {
    int bid = blockIdx.x;
    if (bid < cntBlocks) {
        int e = bid * 256 + threadIdx.x;
        if (e < E) atomicAdd(&degi[__builtin_nontemporal_load(&dst[e])], 1);
    } else {
        int i = (bid - cntBlocks) * 256 + threadIdx.x;
        if (i < 128 * 128) {
            int n = i >> 7, k = i & 127;
            w1t[i] = f2bf(W1[k * 128 + n]);
        } else if (i < 128 * 128 + 48 * 128) {
            int j = i - 128 * 128;
            int n = j >> 7, k = j & 127;
            w2t[j] = (n < 40) ? f2bf(W2[k * 40 + n]) : (ushort)0;
        }
    }
}

// ---- scan level 1 (+ dinv fused) -----------------------------------------
__global__ __launch_bounds__(256) void k_scan1(const int* __restrict__ in,
                                               int* __restrict__ outp,  // rowptr+1
                                               int* __restrict__ bsums,
                                               float* __restrict__ dinv, int N) {
    __shared__ int sh[256];
    int t = threadIdx.x, b = blockIdx.x;
    int base = b * 1024 + t * 4;
    int v0 = (base + 0 < N) ? in[base + 0] : 0;
    int v1 = (base + 1 < N) ? in[base + 1] : 0;
    int v2 = (base + 2 < N) ? in[base + 2] : 0;
    int v3 = (base + 3 < N) ? in[base + 3] : 0;
    if (base + 0 < N) dinv[base + 0] = rsqrtf((float)v0 + 1.0f);
    if (base + 1 < N) dinv[base + 1] = rsqrtf((float)v1 + 1.0f);
    if (base + 2 < N) dinv[base + 2] = rsqrtf((float)v2 + 1.0f);
    if (base + 3 < N) dinv[base + 3] = rsqrtf((float)v3 + 1.0f);
    int l0 = v0, l1 = l0 + v1, l2 = l1 + v2, l3 = l2 + v3;
    sh[t] = l3;
    __syncthreads();
    int run = l3;
    for (int off = 1; off < 256; off <<= 1) {
        int y = (t >= off) ? sh[t - off] : 0;
        __syncthreads();
        run += y;
        sh[t] = run;
        __syncthreads();
    }
    int excl = run - l3;
    if (base + 0 < N) outp[base + 0] = excl + l0;
    if (base + 1 < N) outp[base + 1] = excl + l1;
    if (base + 2 < N) outp[base + 2] = excl + l2;
    if (base + 3 < N) outp[base + 3] = excl + l3;
    if (t == 255) bsums[b] = run;
}

__global__ __launch_bounds__(256) void k_scan2(const int* __restrict__ bsums,
                                               int* __restrict__ boffs, int nb) {
    __shared__ int sh[256];
    int t = threadIdx.x;
    int v = (t < nb) ? bsums[t] : 0;
    sh[t] = v;
    __syncthreads();
    int run = v;
    for (int off = 1; off < 256; off <<= 1) {
        int y = (t >= off) ? sh[t - off] : 0;
        __syncthreads();
        run += y;
        sh[t] = run;
        __syncthreads();
    }
    boffs[t] = run - v;  // exclusive
}

__global__ __launch_bounds__(256) void k_scan3(int* __restrict__ rowptr,
                                               const int* __restrict__ boffs,
                                               int* __restrict__ cursor, int N) {
    int i = blockIdx.x * 256 + threadIdx.x;
    if (i == 0) { rowptr[0] = 0; cursor[0] = 0; }
    if (i < N) {
        int v = rowptr[1 + i] + boffs[i >> 10];
        rowptr[1 + i] = v;
        if (i + 1 < N) cursor[i + 1] = v;
    }
}

// ---- CSR fill: single 8B packed scatter per edge -------------------------
__global__ __launch_bounds__(256) void k_fill(const int* __restrict__ src,
                                              const int* __restrict__ dst,
                                              const float* __restrict__ dinv, int E,
                                              int* __restrict__ cursor,
                                              int2* __restrict__ pairs) {
    int e = blockIdx.x * 256 + threadIdx.x;
    if (e < E) {
        int d = __builtin_nontemporal_load(&dst[e]);
        int s = __builtin_nontemporal_load(&src[e]);
        float c = dinv[s] * dinv[d];
        int p = atomicAdd(&cursor[d], 1);
        int2 pr;
        pr.x = s;
        pr.y = __float_as_int(c);
        pairs[p] = pr;
    }
}

// ---- GEMM1: A fp32 [M,128] (cast in staging) @ BT bf16 -> C bf16 ---------
template <int NF>
__global__ __launch_bounds__(256) void k_gemm_f32a(const float* __restrict__ A,
                                                   const ushort* __restrict__ BT,
                                                   ushort* __restrict__ C, int M,
                                                   int NCOLS) {
    __shared__ ushort As[64][136];
    __shared__ ushort Bs[NF * 16][136];
    const int tid = threadIdx.x;
    const int m0 = blockIdx.x * 64;
#pragma unroll
    for (int i = 0; i < 4; i++) {  // 1024 chunks of 8 elems (fp32 -> bf16)
        int chunk = tid + i * 256;
        int r = chunk >> 4, c8 = chunk & 15;
        float4 v0 = {0.f, 0.f, 0.f, 0.f}, v1 = {0.f, 0.f, 0.f, 0.f};
        if (m0 + r < M) {
            const float* p = &A[(size_t)(m0 + r) * 128 + c8 * 8];
            v0 = *(const float4*)p;
            v1 = *(const float4*)(p + 4);
        }
        ushort o[8];
        o[0] = f2bf(v0.x); o[1] = f2bf(v0.y); o[2] = f2bf(v0.z); o[3] = f2bf(v0.w);
        o[4] = f2bf(v1.x); o[5] = f2bf(v1.y); o[6] = f2bf(v1.z); o[7] = f2bf(v1.w);
        *(float4*)&As[r][c8 * 8] = *(float4*)o;
    }
#pragma unroll
    for (int i = 0; i < NF; i++) {  // stage B: NF*16 rows x 16 chunks
        int chunk = tid + i * 256;
        int r = chunk >> 4, c = chunk & 15;
        *(float4*)&Bs[r][c * 8] = *(const float4*)&BT[(size_t)r * 128 + c * 8];
    }
    __syncthreads();
    const int wave = tid >> 6, lane = tid & 63;
    const int arow = wave * 16 + (lane & 15);
    const int kgrp = (lane >> 4) * 8;
    f32x4 acc[NF];
#pragma unroll
    for (int i = 0; i < NF; i++) acc[i] = (f32x4){0.f, 0.f, 0.f, 0.f};
#pragma unroll
    for (int kk = 0; kk < 4; kk++) {
        bf16x8 a = *(const bf16x8*)&As[arow][kk * 32 + kgrp];
#pragma unroll
        for (int nf = 0; nf < NF; nf++) {
            bf16x8 b = *(const bf16x8*)&Bs[nf * 16 + (lane & 15)][kk * 32 + kgrp];
            acc[nf] = __builtin_amdgcn_mfma_f32_16x16x32_bf16(a, b, acc[nf], 0, 0, 0);
        }
    }
    const int orow = m0 + wave * 16 + (lane >> 4) * 4;
#pragma unroll
    for (int nf = 0; nf < NF; nf++) {
        int col = nf * 16 + (lane & 15);
        if (col >= NCOLS) continue;
#pragma unroll
        for (int j = 0; j < 4; j++) {
            int r = orow + j;
            if (r < M) C[(size_t)r * NCOLS + col] = f2bf(acc[nf][j]);
        }
    }
}

// ---- 128-dim aggregation: 2 edges/wave-instruction, LDS-staged pairs -----
// lane = 32*half + l32; half h handles edges (i + 2k + h); each lane loads
// 8B (4 bf16 cols) of its edge's row; halves merged via shfl_xor(32).
template <bool BIAS_RELU>
__global__ __launch_bounds__(256) void k_agg128(const ushort* __restrict__ hin,
                                                const int* __restrict__ rowptr,
                                                const int2* __restrict__ pairs,
                                                const float* __restrict__ dinv,
                                                const float* __restrict__ bias,
                                                ushort* __restrict__ hout, int N) {
    __shared__ int2 sp[4][64];
    const int w = threadIdx.x >> 6;
    const int lane = threadIdx.x & 63;
    const int wid = (blockIdx.x * 256 + threadIdx.x) >> 6;
    if (wid >= N) return;
    const int half = lane >> 5;
    const int l32 = lane & 31;  // 8B-chunk index within 128-col row (32 chunks)
    const uint2v* hu = (const uint2v*)hin;
    const int beg = rowptr[wid], end = rowptr[wid + 1];
    float a0 = 0.f, a1 = 0.f, a2 = 0.f, a3 = 0.f;
    for (int base = beg; base < end; base += 64) {
        int cnt = min(64, end - base);
        if (lane < cnt) sp[w][lane] = pairs[base + lane];  // wave-private chunk
        int i = 0;
        for (; i + 8 <= cnt; i += 8) {  // 8 edges: this half does 4 of them
            uint2v v[4];
            float cw[4];
#pragma unroll
            for (int k = 0; k < 4; k++) {
                int2 p = sp[w][i + 2 * k + half];
                cw[k] = __int_as_float(p.y);
                v[k] = hu[(size_t)p.x * 32 + l32];
            }
#pragma unroll
            for (int k = 0; k < 4; k++) {
                a0 += cw[k] * bflo(v[k].x);
                a1 += cw[k] * bfhi(v[k].x);
                a2 += cw[k] * bflo(v[k].y);
                a3 += cw[k] * bfhi(v[k].y);
            }
        }
        for (; i + half < cnt; i += 2) {  // tail, alternating halves
            int2 p = sp[w][i + half];
            float cw = __int_as_float(p.y);
            uint2v vv = hu[(size_t)p.x * 32 + l32];
            a0 += cw * bflo(vv.x);
            a1 += cw * bfhi(vv.x);
            a2 += cw * bflo(vv.y);
            a3 += cw * bfhi(vv.y);
        }
    }
    a0 += __shfl_xor(a0, 32);
    a1 += __shfl_xor(a1, 32);
    a2 += __shfl_xor(a2, 32);
    a3 += __shfl_xor(a3, 32);
    if (lane < 32) {
        float dn = dinv[wid];
        float ws = dn * dn;
        uint2v sv = hu[(size_t)wid * 32 + l32];
        a0 += ws * bflo(sv.x);
        a1 += ws * bfhi(sv.x);
        a2 += ws * bflo(sv.y);
        a3 += ws * bfhi(sv.y);
        if (BIAS_RELU) {
            float4 bb = *(const float4*)&bias[l32 * 4];
            a0 = fmaxf(a0 + bb.x, 0.f);
            a1 = fmaxf(a1 + bb.y, 0.f);
            a2 = fmaxf(a2 + bb.z, 0.f);
            a3 = fmaxf(a3 + bb.w, 0.f);
        }
        uint2v o;
        o.x = ((uint)f2bf(a1) << 16) | (uint)f2bf(a0);
        o.y = ((uint)f2bf(a3) << 16) | (uint)f2bf(a2);
        __builtin_nontemporal_store(o, &((uint2v*)hout)[(size_t)wid * 32 + l32]);
    }
}

// ---- GEMM2 (hagg row-major @ W2) + bias/relu/segment-pool epilogue -------
__global__ __launch_bounds__(256) void k_gemm2_pool(const ushort* __restrict__ A,
                                                    const ushort* __restrict__ BT,
                                                    const float* __restrict__ b2,
                                                    const int* __restrict__ batch,
                                                    float* __restrict__ pooled,
                                                    int M) {
    __shared__ ushort As[64][136];
    __shared__ ushort Bs[48][136];
    __shared__ float smC[64][44];
    __shared__ int sbatch[64];
    const int tid = threadIdx.x;
    const int m0 = blockIdx.x * 64;
#pragma unroll
    for (int i = 0; i < 4; i++) {  // stage A row-major
        int chunk = tid + i * 256;
        int r = chunk >> 4, c = chunk & 15;
        float4 v = {0.f, 0.f, 0.f, 0.f};
        if (m0 + r < M) v = *(const float4*)&A[((size_t)(m0 + r)) * 128 + c * 8];
        *(float4*)&As[r][c * 8] = v;
    }
#pragma unroll
    for (int i = 0; i < 3; i++) {  // stage B (w2t)
        int chunk = tid + i * 256;
        int r = chunk >> 4, c = chunk & 15;
        *(float4*)&Bs[r][c * 8] = *(const float4*)&BT[(size_t)r * 128 + c * 8];
    }
    if (tid < 64) sbatch[tid] = (m0 + tid < M) ? batch[m0 + tid] : -1;
    __syncthreads();
    const int wave = tid >> 6, lane = tid & 63;
    const int arow = wave * 16 + (lane & 15);
    const int kgrp = (lane >> 4) * 8;
    f32x4 acc[3];
#pragma unroll
    for (int i = 0; i < 3; i++) acc[i] = (f32x4){0.f, 0.f, 0.f, 0.f};
#pragma unroll
    for (int kk = 0; kk < 4; kk++) {
        bf16x8 a = *(const bf16x8*)&As[arow][kk * 32 + kgrp];
#pragma unroll
        for (int nf = 0; nf < 3; nf++) {
            bf16x8 b = *(const bf16x8*)&Bs[nf * 16 + (lane & 15)][kk * 32 + kgrp];
            acc[nf] = __builtin_amdgcn_mfma_f32_16x16x32_bf16(a, b, acc[nf], 0, 0, 0);
        }
    }
    const int orowl = wave * 16 + (lane >> 4) * 4;  // local row in tile
#pragma unroll
    for (int nf = 0; nf < 3; nf++) {
        int col = nf * 16 + (lane & 15);
        if (col < 40) {
#pragma unroll
            for (int j = 0; j < 4; j++) smC[orowl + j][col] = acc[nf][j];
        }
    }
    __syncthreads();
    // segment-pool 16 rows per quarter-wave, run-length over sorted batch ids
    int q = tid >> 6, c = tid & 63;
    if (c < 40) {
        float bc = b2[c];
        float run = 0.f;
        int curg = -1;
        for (int r = q * 16; r < q * 16 + 16; ++r) {
            int gid = sbatch[r];
            if (gid < 0) break;
            float v = fmaxf(smC[r][c] + bc, 0.f);
            if (gid != curg) {
                if (curg >= 0) atomicAdd(&pooled[(size_t)curg * 40 + c], run);
                curg = gid;
                run = v;
            } else {
                run += v;
            }
        }
        if (curg >= 0) atomicAdd(&pooled[(size_t)curg * 40 + c], run);
    }
}

// ---- finish: mean + log_softmax ------------------------------------------
__global__ __launch_bounds__(64) void k_finish(const float* __restrict__ pooled,
                                               const int* __restrict__ batch, int N,
                                               int DOUT, float* __restrict__ out) {
    int g = blockIdx.x;
    int c = threadIdx.x;
    int lo = 0, hi = N;
    while (lo < hi) {
        int mid = (lo + hi) >> 1;
        if (batch[mid] < g) lo = mid + 1; else hi = mid;
    }
    int start = lo;
    hi = N;
    int lo2 = lo;
    while (lo2 < hi) {
        int mid = (lo2 + hi) >> 1;
        if (batch[mid] <= g) lo2 = mid + 1; else hi = mid;
    }
    int cnt = lo2 - start;
    float v = (c < DOUT) ? pooled[(size_t)g * DOUT + c] / fmaxf((float)cnt, 1.f) : -1e30f;
    float m = v;
#pragma unroll
    for (int o = 32; o; o >>= 1) m = fmaxf(m, __shfl_xor(m, o));
    float ex = (c < DOUT) ? expf(v - m) : 0.f;
    float s = ex;
#pragma unroll
    for (int o = 32; o; o >>= 1) s += __shfl_xor(s, o);
    if (c < DOUT) out[(size_t)g * DOUT + c] = (v - m) - logf(s);
}

extern "C" void kernel_launch(void* const* d_in, const int* in_sizes, int n_in,
                              void* d_out, int out_size, void* d_ws, size_t ws_size,
                              hipStream_t stream) {
    const float* x = (const float*)d_in[0];
    const int* src = (const int*)d_in[1];
    const int* dst = (const int*)d_in[2];
    const int* batch = (const int*)d_in[3];
    const float* W1 = (const float*)d_in[4];
    const float* b1 = (const float*)d_in[5];
    const float* W2 = (const float*)d_in[6];
    const float* b2 = (const float*)d_in[7];
    float* out = (float*)d_out;

    const int N = in_sizes[3];
    const int E = in_sizes[1];
    const int DOUT = in_sizes[7];
    const int G = out_size / DOUT;

    char* ws = (char*)d_ws;
    size_t off = 0;
    auto alloc = [&](size_t bytes) -> char* {
        char* p = ws + off;
        off += (bytes + 255) & ~(size_t)255;
        return p;
    };
    ushort* h1b = (ushort*)alloc((size_t)N * 128 * 2);   // reused as hagg
    ushort* hrelu = (ushort*)alloc((size_t)N * 128 * 2);
    int2* pairs = (int2*)alloc((size_t)E * 8);
    int* degi = (int*)alloc((size_t)N * 4);
    int* rowptr = (int*)alloc((size_t)(N + 1) * 4);
    int* cursor = (int*)alloc((size_t)N * 4);
    float* dinv = (float*)alloc((size_t)N * 4);
    int* bsums = (int*)alloc(256 * 4);
    int* boffs = (int*)alloc(256 * 4);
    ushort* w1t = (ushort*)alloc(128 * 128 * 2);
    ushort* w2t = (ushort*)alloc(48 * 128 * 2);
    float* pooled = (float*)alloc((size_t)G * DOUT * 4);

    ushort* hagg = h1b;  // h1b dead after first agg128

    hipMemsetAsync(degi, 0, (size_t)N * 4, stream);
    hipMemsetAsync(pooled, 0, (size_t)G * DOUT * 4, stream);

    const int TB = 256;
    const int cntB = (E + TB - 1) / TB;
    const int prepB = (128 * 128 + 48 * 128 + TB - 1) / TB;
    k_count_prep<<<cntB + prepB, TB, 0, stream>>>(dst, E, degi, W1, W2, w1t, w2t, cntB);

    int nb = (N + 1023) / 1024;
    k_scan1<<<nb, TB, 0, stream>>>(degi, rowptr + 1, bsums, dinv, N);
    k_scan2<<<1, TB, 0, stream>>>(bsums, boffs, nb);
    k_scan3<<<(N + TB - 1) / TB, TB, 0, stream>>>(rowptr, boffs, cursor, N);
    k_fill<<<(E + TB - 1) / TB, TB, 0, stream>>>(src, dst, dinv, E, cursor, pairs);

    // h1b = bf16(x) @ W1
    k_gemm_f32a<8><<<(N + 63) / 64, TB, 0, stream>>>(x, w1t, h1b, N, 128);
    // hrelu = relu(agg(h1b) + b1)
    k_agg128<true><<<(N + 3) / 4, TB, 0, stream>>>(h1b, rowptr, pairs, dinv, b1,
                                                   hrelu, N);
    // hagg = agg(hrelu)   (linearity: agg(hrelu) @ W2 == agg(hrelu @ W2))
    k_agg128<false><<<(N + 3) / 4, TB, 0, stream>>>(hrelu, rowptr, pairs, dinv,
                                                    nullptr, hagg, N);
    // pooled += relu(hagg @ W2 + b2) per graph (fused epilogue)
    k_gemm2_pool<<<(N + 63) / 64, TB, 0, stream>>>(hagg, w2t, b2, batch, pooled, N);
    // mean + log_softmax
    k_finish<<<G, 64, 0, stream>>>(pooled, batch, N, DOUT, out);
}